// Round 14
// baseline (72.478 us; speedup 1.0000x reference)
//
#include <hip/hip_runtime.h>
#include <hip/hip_bf16.h>

#define LB 2048
#define DB 256
#define HB 8
#define KB 64
#define BH 32     // B*H
#define NG 35     // interpolation grid points: i_g = 64*(g-1), g=0..34
#define NCHUNK 16 // m-chunks in conv (128 m each)

typedef __attribute__((ext_vector_type(8))) short short8;
typedef __attribute__((ext_vector_type(4))) short short4v;
typedef __attribute__((ext_vector_type(4))) float floatx4;

static __device__ __forceinline__ short bfbits(float f) {
    __hip_bfloat16 h = __float2bfloat16(f);
    return *reinterpret_cast<short*>(&h);
}

// ---------------- prep: x fp32 [8192][256] -> bf16 fragment tiles [512][4096]
__global__ __launch_bounds__(256) void prep_x(const float* __restrict__ x,
                                              __hip_bfloat16* __restrict__ xb)
{
    const int t   = blockIdx.x;               // 16-row tile
    const int ksg = threadIdx.x & 31;         // k-chunk (8 floats)
#pragma unroll
    for (int p = 0; p < 2; ++p) {
        const int l = (threadIdx.x >> 5) + 8 * p;
        const float* src = x + (size_t)(t * 16 + l) * DB + ksg * 8;
        const float4 v0 = *reinterpret_cast<const float4*>(src);
        const float4 v1 = *reinterpret_cast<const float4*>(src + 4);
        short8 o;
        o[0] = bfbits(v0.x); o[1] = bfbits(v0.y); o[2] = bfbits(v0.z); o[3] = bfbits(v0.w);
        o[4] = bfbits(v1.x); o[5] = bfbits(v1.y); o[6] = bfbits(v1.z); o[7] = bfbits(v1.w);
        *(reinterpret_cast<short8*>(xb + (size_t)t * 4096) + (ksg * 16 + l)) = o;
    }
}

// ---------------- prep: W [256][512] -> transposed bf16 fragment tiles
__global__ __launch_bounds__(256) void prep_w(const float* __restrict__ Wq,
                                              const float* __restrict__ Wk,
                                              __hip_bfloat16* __restrict__ wb)
{
    const int blk = blockIdx.x;               // 0..63
    const float* W = (blk & 32) ? Wk : Wq;
    const int nbase = (blk & 31) * 16;
#pragma unroll
    for (int cc = 0; cc < 2; ++cc) {
        const int c  = threadIdx.x + cc * 256;
        const int n  = nbase + (c & 15);
        const int k0 = (c >> 4) * 8;
        short8 o;
#pragma unroll
        for (int e = 0; e < 8; ++e) o[e] = bfbits(W[(size_t)(k0 + e) * 512 + n]);
        *(reinterpret_cast<short8*>(wb + (size_t)blk * 4096) + c) = o;
    }
}

// ---------------- prior at the 35 node offsets: prtab[h][g][m] = {pr, pr*d}
// pr = 0.125 * gaussian_h(d), d = m - 64*(g-1)
__global__ __launch_bounds__(256) void prtab_build(const float* __restrict__ pm,
                                                   const float* __restrict__ ls,
                                                   float2* __restrict__ prtab)
{
    const int h = blockIdx.x / NG;
    const int g = blockIdx.x % NG;
    const float mu        = pm[h];
    const float inv_sigma = __expf(-ls[h]);
    const float coef = 0.125f * inv_sigma * (1.0f / 2.5066282f);
    const float ig = (float)(64 * (g - 1));
    float2* dst = prtab + ((size_t)(h * NG + g) << 11);
    for (int m = threadIdx.x; m < LB; m += 256) {
        const float d = (float)m - ig;
        const float t = (d - mu) * inv_sigma;
        const float p = coef * __expf(-0.5f * t * t);
        dst[m] = make_float2(p, p * d);
    }
}

// ---------------- projection GEMM via MFMA; stores q/k row-major bf16 [BH][L][64]
__global__ __launch_bounds__(256) void proj_mfma(
    const __hip_bfloat16* __restrict__ xb, const __hip_bfloat16* __restrict__ wb,
    const float* __restrict__ bq, const float* __restrict__ bk,
    __hip_bfloat16* __restrict__ qf, __hip_bfloat16* __restrict__ kf)
{
    const int rt   = blockIdx.x;              // 64-row block
    const int cg   = blockIdx.y;              // 128-col group
    const int wave = threadIdx.x >> 6;
    const int lane = threadIdx.x & 63;
    const int kg   = lane >> 4;
    const int l    = lane & 15;

    const short8* xp = reinterpret_cast<const short8*>(xb)
                     + (size_t)(rt * 4 + wave) * 512 + lane;
    short8 a[8];
#pragma unroll
    for (int kb = 0; kb < 8; ++kb) a[kb] = xp[kb * 64];

    const int b_     = rt >> 5;               // batch
    const int tile_l = (rt & 31) * 4 + wave;  // 16-row tile index within [B,L]
    const int gct0   = cg * 8;
    const short8* wp = reinterpret_cast<const short8*>(wb) + lane;

    short8 wA[8], wB[8];
#pragma unroll
    for (int kb = 0; kb < 8; ++kb) wA[kb] = wp[(size_t)(gct0 * 8 + kb) * 64];

    // D-fragment mapping (verified R4-R13): value (r) -> row l (lane&15),
    // ch = (ctm&3)*16 + 4*kg + r  of head h = ctm>>2.
#define PROJ_STEP(CURW, NXTW, CT)                                                     \
    {                                                                                 \
        if ((CT) < 7) {                                                               \
            _Pragma("unroll")                                                         \
            for (int kb = 0; kb < 8; ++kb)                                            \
                NXTW[kb] = wp[(size_t)((gct0 + (CT) + 1) * 8 + kb) * 64];             \
        }                                                                             \
        floatx4 acc = {0.f, 0.f, 0.f, 0.f};                                           \
        _Pragma("unroll")                                                             \
        for (int kb = 0; kb < 8; ++kb)                                                \
            acc = __builtin_amdgcn_mfma_f32_16x16x32_bf16(CURW[kb], a[kb], acc, 0, 0, 0); \
        const int gct = gct0 + (CT);                                                  \
        const int m   = gct >> 5;                                                     \
        const int ctm = gct & 31;                                                     \
        const int h   = ctm >> 2;                                                     \
        const float bias = (m ? bk : bq)[h];                                          \
        __hip_bfloat16* outp = m ? kf : qf;                                           \
        const int ch = (ctm & 3) * 16 + 4 * kg;                                       \
        const size_t dst = ((((size_t)(b_ * HB + h) << 11) + tile_l * 16 + l) << 6) + ch; \
        short4v o;                                                                    \
        _Pragma("unroll")                                                             \
        for (int r = 0; r < 4; ++r) o[r] = bfbits(acc[r] + bias);                     \
        *reinterpret_cast<short4v*>(outp + dst) = o;                                  \
    }

    PROJ_STEP(wA, wB, 0)
    PROJ_STEP(wB, wA, 1)
    PROJ_STEP(wA, wB, 2)
    PROJ_STEP(wB, wA, 3)
    PROJ_STEP(wA, wB, 4)
    PROJ_STEP(wB, wA, 5)
    PROJ_STEP(wA, wB, 6)
    PROJ_STEP(wB, wA, 7)
#undef PROJ_STEP
}

// ---------------- conv: G1/G2 at the 35 grid points (partial over m-chunks)
// block = (bh, chunk of 128 m), 256 thr = 4 waves (wave = 32 m), lane = ch.
// a[g] += k*pr, a[NG+g] += k*pr*d; prior broadcast from LDS.
__global__ __launch_bounds__(256) void conv_part(
    const __hip_bfloat16* __restrict__ kf, const float2* __restrict__ prtab,
    float* __restrict__ gpart)
{
    __shared__ float lds_f[17920];   // phase 1: prtab chunk (4480 float2); phase 2: 4 slabs

    const int bh = blockIdx.x;       // 0..31
    const int ck = blockIdx.y;       // 0..NCHUNK-1
    const int h  = bh & 7;
    const int mbase = ck * 128;
    const int wv   = threadIdx.x >> 6;
    const int lane = threadIdx.x & 63;

    // stage prtab[h][g][mbase..mbase+128) -> pl[g][ml]
    {
        const float2* src = prtab + (((size_t)h * NG) << 11) + mbase;
        float2* pl = reinterpret_cast<float2*>(lds_f);
        for (int j = threadIdx.x; j < NG * 128; j += 256) {
            const int g = j >> 7, ml = j & 127;
            pl[j] = src[(size_t)g * 2048 + ml];
        }
    }
    __syncthreads();

    float acc[2 * NG];
#pragma unroll
    for (int i = 0; i < 2 * NG; ++i) acc[i] = 0.f;

    const __hip_bfloat16* kp = kf + (((size_t)bh << 11) + mbase + wv * 32) * 64 + lane;
    const float2* pl = reinterpret_cast<const float2*>(lds_f);

    for (int ml = 0; ml < 32; ++ml) {
        const float kv = __bfloat162float(kp[(size_t)ml * 64]);
        const float2* prow = pl + (wv * 32 + ml);
#pragma unroll
        for (int g = 0; g < NG; ++g) {
            const float2 p = prow[g * 128];    // uniform addr -> LDS broadcast
            acc[g]      = fmaf(kv, p.x, acc[g]);
            acc[NG + g] = fmaf(kv, p.y, acc[NG + g]);
        }
    }
    __syncthreads();   // done reading pl; reuse LDS for reduction slabs

#pragma unroll
    for (int i = 0; i < 2 * NG; ++i) lds_f[(wv * 70 + i) * 64 + lane] = acc[i];
    __syncthreads();

    float* gp = gpart + (size_t)(bh * NCHUNK + ck) * (2 * NG * 64);
    for (int j = threadIdx.x; j < 2 * NG * 64; j += 256)
        gp[j] = lds_f[j] + lds_f[4480 + j] + lds_f[8960 + j] + lds_f[13440 + j];
}

// ---------------- combine chunks: gw[bh][type][g][ch]
__global__ __launch_bounds__(256) void conv_combine(const float* __restrict__ gpart,
                                                    float* __restrict__ gw)
{
    const int j   = blockIdx.x * 256 + threadIdx.x;   // 0 .. 32*4480-1 (grid exact)
    const int bh  = j / 4480;
    const int idx = j - bh * 4480;
    const float* gp = gpart + (size_t)bh * NCHUNK * 4480 + idx;
    float s = 0.f;
#pragma unroll
    for (int c = 0; c < NCHUNK; ++c) s += gp[(size_t)c * 4480];
    gw[j] = s;
}

// ---------------- final: per row i, Catmull-Rom interp of G1/G2 + q-dot
// wave = one row; lane = ch. out = (C_i + q.G2(i)) / (2048 + q.G1(i))
__global__ __launch_bounds__(256) void final_kernel(
    const __hip_bfloat16* __restrict__ qf, const float* __restrict__ gw,
    float* __restrict__ out)
{
    const int wid  = blockIdx.x * 4 + (threadIdx.x >> 6);  // 0..65535 = bh*2048 + i
    const int lane = threadIdx.x & 63;
    const int bh   = wid >> 11;
    const int i    = wid & (LB - 1);
    const int b    = bh >> 3;
    const int h    = bh & 7;

    const float qv = __bfloat162float(qf[((size_t)wid << 6) + lane]);

    const int   cell = i >> 6;                 // 0..31
    const float u  = (float)(i & 63) * (1.0f / 64.0f);
    const float u2 = u * u, u3 = u2 * u;
    const float c0 = -0.5f * u + u2 - 0.5f * u3;
    const float c1 = 1.0f - 2.5f * u2 + 1.5f * u3;
    const float c2 = 0.5f * u + 2.0f * u2 - 1.5f * u3;
    const float c3 = -0.5f * u2 + 0.5f * u3;

    const float* g1 = gw + ((size_t)(bh * 2 + 0) * NG + cell) * 64 + lane;
    const float* g2 = gw + ((size_t)(bh * 2 + 1) * NG + cell) * 64 + lane;
    const float G1 = c0 * g1[0] + c1 * g1[64] + c2 * g1[128] + c3 * g1[192];
    const float G2 = c0 * g2[0] + c1 * g2[64] + c2 * g2[128] + c3 * g2[192];

    float D = qv * G1;
    float N = qv * G2;
#pragma unroll
    for (int off = 32; off >= 1; off >>= 1) {
        D += __shfl_xor(D, off, 64);
        N += __shfl_xor(N, off, 64);
    }
    if (lane == 0) {
        const float C = (float)(2096128 - 2048 * i);   // sum_m (m - i), exact
        out[((size_t)(b * LB + i)) * HB + h] = (C + N) / (2048.0f + D);
    }
}

extern "C" void kernel_launch(void* const* d_in, const int* in_sizes, int n_in,
                              void* d_out, int out_size, void* d_ws, size_t ws_size,
                              hipStream_t stream) {
    const float* x  = (const float*)d_in[0];
    const float* Wq = (const float*)d_in[1];
    const float* bq = (const float*)d_in[2];
    const float* Wk = (const float*)d_in[3];
    const float* bk = (const float*)d_in[4];
    const float* pm = (const float*)d_in[5];
    const float* ls = (const float*)d_in[6];
    float* out = (float*)d_out;

    char* w = (char*)d_ws;
    __hip_bfloat16* xbuf  = (__hip_bfloat16*)w;                    w += (size_t)8192 * 256 * 2;   // 4.2 MB
    __hip_bfloat16* wbuf  = (__hip_bfloat16*)w;                    w += (size_t)64 * 4096 * 2;    // 0.5 MB
    __hip_bfloat16* qf    = (__hip_bfloat16*)w;                    w += (size_t)BH * LB * 64 * 2; // 8.4 MB
    __hip_bfloat16* kf    = (__hip_bfloat16*)w;                    w += (size_t)BH * LB * 64 * 2; // 8.4 MB
    float2*         prtab = (float2*)w;                            w += (size_t)8 * NG * 2048 * 8;  // 4.6 MB
    float*          gpart = (float*)w;                             w += (size_t)BH * NCHUNK * 2 * NG * 64 * 4; // 9.2 MB
    float*          gw    = (float*)w;                             // 0.6 MB

    prep_x<<<dim3(512), dim3(256), 0, stream>>>(x, xbuf);
    prep_w<<<dim3(64), dim3(256), 0, stream>>>(Wq, Wk, wbuf);
    prtab_build<<<dim3(8 * NG), dim3(256), 0, stream>>>(pm, ls, prtab);
    proj_mfma<<<dim3(128, 8), dim3(256), 0, stream>>>(xbuf, wbuf, bq, bk, qf, kf);
    conv_part<<<dim3(32, NCHUNK), dim3(256), 0, stream>>>(kf, prtab, gpart);
    conv_combine<<<dim3(560), dim3(256), 0, stream>>>(gpart, gw);
    final_kernel<<<dim3(16384), dim3(256), 0, stream>>>(qf, gw, out);
}

// Round 15
// 61.257 us; speedup vs baseline: 1.1832x; 1.1832x over previous
//
#include <hip/hip_runtime.h>
#include <hip/hip_bf16.h>

#define LB 2048
#define DB 256
#define HB 8
#define BH 32     // B*H
#define NG 19     // grid nodes: i_g = 128*(g-1), g=0..18
#define NCHUNK 8  // m-chunks in conv (256 m each)

typedef __attribute__((ext_vector_type(8))) short short8;
typedef __attribute__((ext_vector_type(4))) short short4v;
typedef __attribute__((ext_vector_type(4))) float floatx4;

static __device__ __forceinline__ short bfbits(float f) {
    __hip_bfloat16 h = __float2bfloat16(f);
    return *reinterpret_cast<short*>(&h);
}

// ---------------- prep: x fp32 [8192][256] -> bf16 fragment tiles [512][4096]
__global__ __launch_bounds__(256) void prep_x(const float* __restrict__ x,
                                              __hip_bfloat16* __restrict__ xb)
{
    const int t   = blockIdx.x;
    const int ksg = threadIdx.x & 31;
#pragma unroll
    for (int p = 0; p < 2; ++p) {
        const int l = (threadIdx.x >> 5) + 8 * p;
        const float* src = x + (size_t)(t * 16 + l) * DB + ksg * 8;
        const float4 v0 = *reinterpret_cast<const float4*>(src);
        const float4 v1 = *reinterpret_cast<const float4*>(src + 4);
        short8 o;
        o[0] = bfbits(v0.x); o[1] = bfbits(v0.y); o[2] = bfbits(v0.z); o[3] = bfbits(v0.w);
        o[4] = bfbits(v1.x); o[5] = bfbits(v1.y); o[6] = bfbits(v1.z); o[7] = bfbits(v1.w);
        *(reinterpret_cast<short8*>(xb + (size_t)t * 4096) + (ksg * 16 + l)) = o;
    }
}

// ---------------- prep: W [256][512] -> transposed bf16 fragment tiles
__global__ __launch_bounds__(256) void prep_w(const float* __restrict__ Wq,
                                              const float* __restrict__ Wk,
                                              __hip_bfloat16* __restrict__ wb)
{
    const int blk = blockIdx.x;
    const float* W = (blk & 32) ? Wk : Wq;
    const int nbase = (blk & 31) * 16;
#pragma unroll
    for (int cc = 0; cc < 2; ++cc) {
        const int c  = threadIdx.x + cc * 256;
        const int n  = nbase + (c & 15);
        const int k0 = (c >> 4) * 8;
        short8 o;
#pragma unroll
        for (int e = 0; e < 8; ++e) o[e] = bfbits(W[(size_t)(k0 + e) * 512 + n]);
        *(reinterpret_cast<short8*>(wb + (size_t)blk * 4096) + c) = o;
    }
}

// ---------------- projection GEMM via MFMA; row-major out via LDS transpose
__global__ __launch_bounds__(256) void proj_mfma(
    const __hip_bfloat16* __restrict__ xb, const __hip_bfloat16* __restrict__ wb,
    const float* __restrict__ bq, const float* __restrict__ bk,
    __hip_bfloat16* __restrict__ qf, __hip_bfloat16* __restrict__ kf)
{
    __shared__ __align__(16) __hip_bfloat16 ot[64][136];

    const int rt   = blockIdx.x;
    const int cg   = blockIdx.y;              // 0-3: q, 4-7: k
    const int wave = threadIdx.x >> 6;
    const int lane = threadIdx.x & 63;
    const int kg   = lane >> 4;
    const int l    = lane & 15;

    const short8* xp = reinterpret_cast<const short8*>(xb)
                     + (size_t)(rt * 4 + wave) * 512 + lane;
    short8 a[8];
#pragma unroll
    for (int kb = 0; kb < 8; ++kb) a[kb] = xp[kb * 64];

    const int b_   = rt >> 5;
    const int gct0 = cg * 8;
    const short8* wp = reinterpret_cast<const short8*>(wb) + lane;

    short8 wA[8], wB[8];
#pragma unroll
    for (int kb = 0; kb < 8; ++kb) wA[kb] = wp[(size_t)(gct0 * 8 + kb) * 64];

#define PROJ_STEP(CURW, NXTW, CT)                                                     \
    {                                                                                 \
        if ((CT) < 7) {                                                               \
            _Pragma("unroll")                                                         \
            for (int kb = 0; kb < 8; ++kb)                                            \
                NXTW[kb] = wp[(size_t)((gct0 + (CT) + 1) * 8 + kb) * 64];             \
        }                                                                             \
        floatx4 acc = {0.f, 0.f, 0.f, 0.f};                                           \
        _Pragma("unroll")                                                             \
        for (int kb = 0; kb < 8; ++kb)                                                \
            acc = __builtin_amdgcn_mfma_f32_16x16x32_bf16(CURW[kb], a[kb], acc, 0, 0, 0); \
        const int h   = ((gct0 + (CT)) & 31) >> 2;                                    \
        const float bias = (cg < 4 ? bq : bk)[h];                                     \
        short4v o;                                                                    \
        _Pragma("unroll")                                                             \
        for (int r = 0; r < 4; ++r) o[r] = bfbits(acc[r] + bias);                     \
        *reinterpret_cast<short4v*>(&ot[wave * 16 + l][(CT) * 16 + 4 * kg]) = o;      \
    }

    PROJ_STEP(wA, wB, 0)
    PROJ_STEP(wB, wA, 1)
    PROJ_STEP(wA, wB, 2)
    PROJ_STEP(wB, wA, 3)
    PROJ_STEP(wA, wB, 4)
    PROJ_STEP(wB, wA, 5)
    PROJ_STEP(wA, wB, 6)
    PROJ_STEP(wB, wA, 7)
#undef PROJ_STEP

    __syncthreads();

    __hip_bfloat16* outp = (cg < 4) ? qf : kf;
    const int h0 = (cg & 3) * 2;
    const int rbase = (rt & 31) * 64;
#pragma unroll
    for (int it = 0; it < 8; ++it) {
        const int cidx = threadIdx.x + it * 256;
        const int row  = cidx >> 5;
        const int sub  = cidx & 31;
        const int hoff = sub >> 4;
        const int ch64 = (sub & 15) * 4;
        const short4v v = *reinterpret_cast<const short4v*>(&ot[row][sub * 4]);
        const size_t dst = (((size_t)(b_ * HB + h0 + hoff) << 11) + rbase + row) * 64 + ch64;
        *reinterpret_cast<short4v*>(outp + dst) = v;
    }
}

// ---------------- conv: G1/G2 partials at 19 nodes, prior fused, per-wave chunks
// block = (bh, 256-m chunk); wave wv handles m in [wv*64, +64); lane = ch.
__global__ __launch_bounds__(256) void conv_part(
    const __hip_bfloat16* __restrict__ kf,
    const float* __restrict__ pm, const float* __restrict__ ls,
    float* __restrict__ gpart)
{
    __shared__ float pl[256][40];    // [ml][2g: P, P*d] (38 used) = 40 KB

    const int bh    = blockIdx.x;    // 0..31
    const int ck    = blockIdx.y;    // 0..7
    const int h     = bh & 7;
    const int mbase = ck * 256;
    const int wv    = threadIdx.x >> 6;
    const int lane  = threadIdx.x & 63;

    {
        const float mu        = pm[h];
        const float inv_sigma = __expf(-ls[h]);
        const float coef = 0.125f * inv_sigma * (1.0f / 2.5066282f);
        for (int idx = threadIdx.x; idx < NG * 256; idx += 256) {
            const int g  = idx >> 8;
            const int ml = idx & 255;
            const float d = (float)(mbase + ml - 128 * g + 128);   // m - node(g)
            const float t = (d - mu) * inv_sigma;
            const float p = coef * __expf(-0.5f * t * t);
            *reinterpret_cast<float2*>(&pl[ml][2 * g]) = make_float2(p, p * d);
        }
    }
    __syncthreads();

    float acc_e[NG], acc_w[NG];
#pragma unroll
    for (int g = 0; g < NG; ++g) { acc_e[g] = 0.f; acc_w[g] = 0.f; }

    const __hip_bfloat16* kp = kf + (((size_t)bh << 11) + mbase + wv * 64) * 64 + lane;

    for (int ml = 0; ml < 64; ++ml) {
        const float kv = __bfloat162float(kp[(size_t)ml * 64]);
        const float* prow = &pl[wv * 64 + ml][0];
#pragma unroll
        for (int g2 = 0; g2 < 9; ++g2) {
            const float4 f = *reinterpret_cast<const float4*>(prow + 4 * g2);
            acc_e[2 * g2]     = fmaf(kv, f.x, acc_e[2 * g2]);
            acc_w[2 * g2]     = fmaf(kv, f.y, acc_w[2 * g2]);
            acc_e[2 * g2 + 1] = fmaf(kv, f.z, acc_e[2 * g2 + 1]);
            acc_w[2 * g2 + 1] = fmaf(kv, f.w, acc_w[2 * g2 + 1]);
        }
        const float2 f18 = *reinterpret_cast<const float2*>(prow + 36);
        acc_e[18] = fmaf(kv, f18.x, acc_e[18]);
        acc_w[18] = fmaf(kv, f18.y, acc_w[18]);
    }

    // per-(wave,chunk) partial slab: gpart[bh][ck][wv][g*128 + type*64 + ch]
    float* gp = gpart + (size_t)((bh * NCHUNK + ck) * 4 + wv) * 2432;
#pragma unroll
    for (int g = 0; g < NG; ++g) {
        gp[g * 128 + lane]      = acc_e[g];
        gp[g * 128 + 64 + lane] = acc_w[g];
    }
}

// ---------------- combine 32 slabs: gw[bh][g][type][ch]
__global__ __launch_bounds__(256) void conv_combine(const float* __restrict__ gpart,
                                                    float* __restrict__ gw)
{
    const int j = blockIdx.x * 256 + threadIdx.x;   // 0 .. 32*2432-1 (exact)
    const int bh  = j / 2432;
    const int idx = j - bh * 2432;
    const float* gp = gpart + (size_t)bh * (NCHUNK * 4) * 2432 + idx;
    float s = 0.f;
#pragma unroll
    for (int c = 0; c < NCHUNK * 4; ++c) s += gp[(size_t)c * 2432];
    gw[j] = s;
}

// ---------------- final: per-row Catmull-Rom interp of G1/G2 + q-dot
__global__ __launch_bounds__(256) void final_kernel(
    const __hip_bfloat16* __restrict__ qf, const float* __restrict__ gw,
    float* __restrict__ out)
{
    const int wid  = blockIdx.x * 4 + (threadIdx.x >> 6);
    const int lane = threadIdx.x & 63;
    const int bh   = wid >> 11;
    const int i    = wid & (LB - 1);
    const int b    = bh >> 3;
    const int h    = bh & 7;

    const float qv = __bfloat162float(qf[((size_t)wid << 6) + lane]);

    const int   cell = i >> 7;
    const float u  = (float)(i & 127) * (1.0f / 128.0f);
    const float u2 = u * u, u3 = u2 * u;
    const float c0 = -0.5f * u + u2 - 0.5f * u3;
    const float c1 = 1.0f - 2.5f * u2 + 1.5f * u3;
    const float c2 = 0.5f * u + 2.0f * u2 - 1.5f * u3;
    const float c3 = -0.5f * u2 + 0.5f * u3;

    const float* gb = gw + (size_t)bh * 2432 + cell * 128 + lane;
    const float G1 = c0 * gb[0]  + c1 * gb[128] + c2 * gb[256] + c3 * gb[384];
    const float G2 = c0 * gb[64] + c1 * gb[192] + c2 * gb[320] + c3 * gb[448];

    float D = qv * G1;
    float N = qv * G2;
#pragma unroll
    for (int off = 32; off >= 1; off >>= 1) {
        D += __shfl_xor(D, off, 64);
        N += __shfl_xor(N, off, 64);
    }
    if (lane == 0) {
        const float C = (float)(2096128 - 2048 * i);
        out[((size_t)(b * LB + i)) * HB + h] = (C + N) / (2048.0f + D);
    }
}

extern "C" void kernel_launch(void* const* d_in, const int* in_sizes, int n_in,
                              void* d_out, int out_size, void* d_ws, size_t ws_size,
                              hipStream_t stream) {
    const float* x  = (const float*)d_in[0];
    const float* Wq = (const float*)d_in[1];
    const float* bq = (const float*)d_in[2];
    const float* Wk = (const float*)d_in[3];
    const float* bk = (const float*)d_in[4];
    const float* pm = (const float*)d_in[5];
    const float* ls = (const float*)d_in[6];
    float* out = (float*)d_out;

    char* w = (char*)d_ws;
    __hip_bfloat16* xbuf = (__hip_bfloat16*)w;  w += (size_t)8192 * 256 * 2;            // 4.2 MB
    __hip_bfloat16* wbuf = (__hip_bfloat16*)w;  w += (size_t)64 * 4096 * 2;             // 0.5 MB
    __hip_bfloat16* qf   = (__hip_bfloat16*)w;  w += (size_t)BH * LB * 64 * 2;          // 8.4 MB
    __hip_bfloat16* kf   = (__hip_bfloat16*)w;  w += (size_t)BH * LB * 64 * 2;          // 8.4 MB
    float*          gpart = (float*)w;          w += (size_t)BH * NCHUNK * 4 * 2432 * 4; // 10.0 MB
    float*          gw    = (float*)w;                                                   // 0.3 MB

    prep_x<<<dim3(512), dim3(256), 0, stream>>>(x, xbuf);
    prep_w<<<dim3(64), dim3(256), 0, stream>>>(Wq, Wk, wbuf);
    proj_mfma<<<dim3(128, 8), dim3(256), 0, stream>>>(xbuf, wbuf, bq, bk, qf, kf);
    conv_part<<<dim3(32, NCHUNK), dim3(256), 0, stream>>>(kf, pm, ls, gpart);
    conv_combine<<<dim3(304), dim3(256), 0, stream>>>(gpart, gw);
    final_kernel<<<dim3(16384), dim3(256), 0, stream>>>(qf, gw, out);
}

// Round 16
// 43.584 us; speedup vs baseline: 1.6629x; 1.4055x over previous
//
#include <hip/hip_runtime.h>
#include <hip/hip_bf16.h>

#define LB 2048
#define DB 256
#define HB 8
#define BH 32     // B*H
#define NG 19     // prior nodes: node g at i = 128*(g-1)
#define NROW 48   // A rows: 0-18 P, 19-37 P*d, 38-47 zero (M padded to 48)
#define NCK 16    // conv K-chunks (128 m each)

typedef __attribute__((ext_vector_type(8))) short short8;
typedef __attribute__((ext_vector_type(4))) short short4v;
typedef __attribute__((ext_vector_type(4))) float floatx4;

static __device__ __forceinline__ short bfbits(float f) {
    __hip_bfloat16 h = __float2bfloat16(f);
    return *reinterpret_cast<short*>(&h);
}

// ---------------- prep_misc: W fragments (blocks 0-63) + prior A-fragments (64-159)
__global__ __launch_bounds__(256) void prep_misc(
    const float* __restrict__ Wq, const float* __restrict__ Wk,
    const float* __restrict__ pm, const float* __restrict__ ls,
    __hip_bfloat16* __restrict__ wb, __hip_bfloat16* __restrict__ prtF)
{
    if (blockIdx.x < 64) {
        const int blk = blockIdx.x;
        const float* W = (blk & 32) ? Wk : Wq;
        const int nbase = (blk & 31) * 16;
#pragma unroll
        for (int cc = 0; cc < 2; ++cc) {
            const int c  = threadIdx.x + cc * 256;
            const int n  = nbase + (c & 15);
            const int k0 = (c >> 4) * 8;
            short8 o;
#pragma unroll
            for (int e = 0; e < 8; ++e) o[e] = bfbits(W[(size_t)(k0 + e) * 512 + n]);
            *(reinterpret_cast<short8*>(wb + (size_t)blk * 4096) + c) = o;
        }
        return;
    }
    // prior A-fragments: blk2 = (h, gt, ms-quarter)
    const int blk2 = blockIdx.x - 64;            // 0..95
    const int h    = blk2 / 12;
    const int rem  = blk2 - h * 12;
    const int gt   = rem >> 2;
    const int msq  = rem & 3;
    const int wv   = threadIdx.x >> 6;
    const int l    = threadIdx.x & 63;

    const float mu        = pm[h];
    const float inv_sigma = __expf(-ls[h]);
    const float coef = 0.125f * inv_sigma * (1.0f / 2.5066282f);

    const int row = gt * 16 + (l & 15);          // A row 0..47
#pragma unroll
    for (int it = 0; it < 4; ++it) {
        const int ms = msq * 16 + wv * 4 + it;   // 0..63
        const int m0 = ms * 32 + (l >> 4) * 8;
        short8 o;
#pragma unroll
        for (int e = 0; e < 8; ++e) {
            float val = 0.f;
            if (row < 38) {
                const int g = (row < 19) ? row : row - 19;
                const float d = (float)(m0 + e - 128 * g + 128);
                const float t = (d - mu) * inv_sigma;
                const float P = coef * __expf(-0.5f * t * t);
                val = (row < 19) ? P : P * d;
            }
            o[e] = bfbits(val);
        }
        reinterpret_cast<short8*>(prtF)[(size_t)((h * 3 + gt) * 64 + ms) * 64 + l] = o;
    }
}

// ---------------- proj: x staged fp32->bf16 in LDS; MFMA; q -> row-major, k -> kT fragments
__global__ __launch_bounds__(256) void proj_fused(
    const float* __restrict__ x, const __hip_bfloat16* __restrict__ wb,
    const float* __restrict__ bq, const float* __restrict__ bk,
    __hip_bfloat16* __restrict__ qf, __hip_bfloat16* __restrict__ kT)
{
    __shared__ __align__(16) char smem[64 * 264 * 2];   // 33.8 KB union
    auto xs = reinterpret_cast<__hip_bfloat16(*)[264]>(smem);
    auto ot = reinterpret_cast<__hip_bfloat16(*)[136]>(smem);

    const int rt   = blockIdx.x;              // 64-row block
    const int cg   = blockIdx.y;              // 0-3: q, 4-7: k
    const int wave = threadIdx.x >> 6;
    const int lane = threadIdx.x & 63;
    const int kg   = lane >> 4;
    const int l15  = lane & 15;

    // stage x rows [rt*64, +64) fp32 -> bf16 LDS (coalesced float4)
#pragma unroll
    for (int it = 0; it < 16; ++it) {
        const int idx = threadIdx.x + it * 256;      // 0..4095
        const int row = idx >> 6;
        const int k4  = (idx & 63) * 4;
        const float4 v = *reinterpret_cast<const float4*>(x + ((size_t)(rt * 64 + row)) * DB + k4);
        short4v o;
        o[0] = bfbits(v.x); o[1] = bfbits(v.y); o[2] = bfbits(v.z); o[3] = bfbits(v.w);
        *reinterpret_cast<short4v*>(&xs[row][k4]) = o;
    }
    __syncthreads();

    // A fragments from LDS (same data layout prep_x produced)
    short8 a[8];
    {
        const __hip_bfloat16* xr = &xs[wave * 16 + l15][0];
#pragma unroll
        for (int kb = 0; kb < 8; ++kb)
            a[kb] = *reinterpret_cast<const short8*>(xr + kb * 32 + (lane >> 4) * 8);
    }
    __syncthreads();   // xs dead; ot may now alias it

    const int b_   = rt >> 5;
    const int gct0 = cg * 8;
    const short8* wp = reinterpret_cast<const short8*>(wb) + lane;

    short8 wA[8], wB[8];
#pragma unroll
    for (int kb = 0; kb < 8; ++kb) wA[kb] = wp[(size_t)(gct0 * 8 + kb) * 64];

#define PROJ_STEP(CURW, NXTW, CT)                                                     \
    {                                                                                 \
        if ((CT) < 7) {                                                               \
            _Pragma("unroll")                                                         \
            for (int kb = 0; kb < 8; ++kb)                                            \
                NXTW[kb] = wp[(size_t)((gct0 + (CT) + 1) * 8 + kb) * 64];             \
        }                                                                             \
        floatx4 acc = {0.f, 0.f, 0.f, 0.f};                                           \
        _Pragma("unroll")                                                             \
        for (int kb = 0; kb < 8; ++kb)                                                \
            acc = __builtin_amdgcn_mfma_f32_16x16x32_bf16(CURW[kb], a[kb], acc, 0, 0, 0); \
        const int h   = ((gct0 + (CT)) & 31) >> 2;                                    \
        const float bias = (cg < 4 ? bq : bk)[h];                                     \
        short4v o;                                                                    \
        _Pragma("unroll")                                                             \
        for (int r = 0; r < 4; ++r) o[r] = bfbits(acc[r] + bias);                     \
        *reinterpret_cast<short4v*>(&ot[wave * 16 + l15][(CT) * 16 + 4 * kg]) = o;    \
    }

    PROJ_STEP(wA, wB, 0)
    PROJ_STEP(wB, wA, 1)
    PROJ_STEP(wA, wB, 2)
    PROJ_STEP(wB, wA, 3)
    PROJ_STEP(wA, wB, 4)
    PROJ_STEP(wB, wA, 5)
    PROJ_STEP(wA, wB, 6)
    PROJ_STEP(wB, wA, 7)
#undef PROJ_STEP

    __syncthreads();

    if (cg < 4) {
        // q: coalesced row-major copy-out (R15-verified path)
        const int h0 = (cg & 3) * 2;
        const int rbase = (rt & 31) * 64;
#pragma unroll
        for (int it = 0; it < 8; ++it) {
            const int cidx = threadIdx.x + it * 256;
            const int row  = cidx >> 5;
            const int sub  = cidx & 31;
            const int hoff = sub >> 4;
            const int ch64 = (sub & 15) * 4;
            const short4v v = *reinterpret_cast<const short4v*>(&ot[row][sub * 4]);
            const size_t dst = (((size_t)(b_ * HB + h0 + hoff) << 11) + rbase + row) * 64 + ch64;
            *reinterpret_cast<short4v*>(qf + dst) = v;
        }
    } else {
        // k: emit kT B-fragments. wave -> (hoff, m-subblock)
        const int hoff = wave >> 1;               // 0..1
        const int msb  = wave & 1;                // 0..1
        const int h0   = (cg & 3) * 2;
        const int bh   = b_ * HB + h0 + hoff;
        const int msG  = (rt & 31) * 2 + msb;     // global 32-m step 0..63
        const int rowb = msb * 32 + (lane >> 4) * 8;
        const int colb = hoff * 64 + l15;         // + ct*16 below
#pragma unroll
        for (int ct = 0; ct < 4; ++ct) {
            short8 o;
#pragma unroll
            for (int e = 0; e < 8; ++e)
                o[e] = *reinterpret_cast<const short*>(&ot[rowb + e][colb + ct * 16]);
            reinterpret_cast<short8*>(kT)[(size_t)((bh * 4 + ct) * 64 + msG) * 64 + lane] = o;
        }
    }
}

// ---------------- conv via MFMA: G[48 x 64] = A(prior)[48 x 2048] . k^T[64 x 2048]^T
// grid (32 bh, 4); wave = one K-chunk of 128 m (4 MFMA steps), 24 MFMAs/wave.
__global__ __launch_bounds__(256, 2) void conv_mfma(
    const __hip_bfloat16* __restrict__ prtF, const __hip_bfloat16* __restrict__ kT,
    float* __restrict__ gpart)
{
    const int bh   = blockIdx.x;
    const int wv   = threadIdx.x >> 6;
    const int lane = threadIdx.x & 63;
    const int ck   = blockIdx.y * 4 + wv;     // 0..15
    const int h    = bh & 7;

    const short8* A = reinterpret_cast<const short8*>(prtF);
    const short8* B = reinterpret_cast<const short8*>(kT);

    floatx4 acc[3][4];
#pragma unroll
    for (int gt = 0; gt < 3; ++gt)
#pragma unroll
        for (int ct = 0; ct < 4; ++ct) acc[gt][ct] = (floatx4){0.f, 0.f, 0.f, 0.f};

#pragma unroll
    for (int s = 0; s < 4; ++s) {
        const int ms = ck * 4 + s;
        short8 af[3], bf[4];
#pragma unroll
        for (int gt = 0; gt < 3; ++gt)
            af[gt] = A[(size_t)((h * 3 + gt) * 64 + ms) * 64 + lane];
#pragma unroll
        for (int ct = 0; ct < 4; ++ct)
            bf[ct] = B[(size_t)((bh * 4 + ct) * 64 + ms) * 64 + lane];
#pragma unroll
        for (int gt = 0; gt < 3; ++gt)
#pragma unroll
            for (int ct = 0; ct < 4; ++ct)
                acc[gt][ct] = __builtin_amdgcn_mfma_f32_16x16x32_bf16(af[gt], bf[ct], acc[gt][ct], 0, 0, 0);
    }

    // C map: row = gt*16 + 4*(lane>>4) + r, col = ct*16 + (lane&15)
    const int kg = lane >> 4, l15 = lane & 15;
    float* gp = gpart + (size_t)(bh * NCK + ck) * (NROW * 64);
#pragma unroll
    for (int gt = 0; gt < 3; ++gt)
#pragma unroll
        for (int ct = 0; ct < 4; ++ct)
#pragma unroll
            for (int r = 0; r < 4; ++r)
                gp[(gt * 16 + 4 * kg + r) * 64 + ct * 16 + l15] = acc[gt][ct][r];
}

// ---------------- combine 16 K-chunks: gw[bh][48][64]
__global__ __launch_bounds__(256) void conv_combine(const float* __restrict__ gpart,
                                                    float* __restrict__ gw)
{
    const int j   = blockIdx.x * 256 + threadIdx.x;   // 0..98303 (grid exact)
    const int bh  = j / 3072;
    const int idx = j - bh * 3072;
    const float* gp = gpart + (size_t)bh * NCK * 3072 + idx;
    float s = 0.f;
#pragma unroll
    for (int c = 0; c < NCK; ++c) s += gp[(size_t)c * 3072];
    gw[j] = s;
}

// ---------------- final: 4 rows/wave; 16 lanes x 4ch; Catmull-Rom over gw rows
__global__ __launch_bounds__(256) void final_kernel(
    const __hip_bfloat16* __restrict__ qf, const float* __restrict__ gw,
    float* __restrict__ out)
{
    const int row = blockIdx.x * 16 + (threadIdx.x >> 4);  // 0..65535 = bh*2048 + i
    const int l15 = threadIdx.x & 15;
    const int bh  = row >> 11;
    const int i   = row & (LB - 1);
    const int b   = bh >> 3;
    const int h   = bh & 7;

    const short4v q4 = reinterpret_cast<const short4v*>(qf)[(size_t)row * 16 + l15];
    float q[4];
#pragma unroll
    for (int e = 0; e < 4; ++e) {
        const unsigned short u16 = (unsigned short)q4[e];
        const unsigned int bits = ((unsigned int)u16) << 16;
        q[e] = __builtin_bit_cast(float, bits);
    }

    const int   cell = i >> 7;
    const float u  = (float)(i & 127) * (1.0f / 128.0f);
    const float u2 = u * u, u3 = u2 * u;
    const float c0 = -0.5f * u + u2 - 0.5f * u3;
    const float c1 = 1.0f - 2.5f * u2 + 1.5f * u3;
    const float c2 = 0.5f * u + 2.0f * u2 - 1.5f * u3;
    const float c3 = -0.5f * u2 + 0.5f * u3;

    const float4* g4 = reinterpret_cast<const float4*>(gw + (size_t)bh * 3072) + l15;
    const float4 n0 = g4[(cell + 0) * 16], n1 = g4[(cell + 1) * 16];
    const float4 n2 = g4[(cell + 2) * 16], n3 = g4[(cell + 3) * 16];
    const float4 w0 = g4[(19 + cell + 0) * 16], w1 = g4[(19 + cell + 1) * 16];
    const float4 w2 = g4[(19 + cell + 2) * 16], w3 = g4[(19 + cell + 3) * 16];

    float D = q[0] * (c0 * n0.x + c1 * n1.x + c2 * n2.x + c3 * n3.x)
            + q[1] * (c0 * n0.y + c1 * n1.y + c2 * n2.y + c3 * n3.y)
            + q[2] * (c0 * n0.z + c1 * n1.z + c2 * n2.z + c3 * n3.z)
            + q[3] * (c0 * n0.w + c1 * n1.w + c2 * n2.w + c3 * n3.w);
    float N = q[0] * (c0 * w0.x + c1 * w1.x + c2 * w2.x + c3 * w3.x)
            + q[1] * (c0 * w0.y + c1 * w1.y + c2 * w2.y + c3 * w3.y)
            + q[2] * (c0 * w0.z + c1 * w1.z + c2 * w2.z + c3 * w3.z)
            + q[3] * (c0 * w0.w + c1 * w1.w + c2 * w2.w + c3 * w3.w);

#pragma unroll
    for (int off = 8; off >= 1; off >>= 1) {
        D += __shfl_xor(D, off, 64);
        N += __shfl_xor(N, off, 64);
    }
    if (l15 == 0) {
        const float C = (float)(2096128 - 2048 * i);   // sum_m (m - i), exact
        out[((size_t)(b * LB + i)) * HB + h] = (C + N) / (2048.0f + D);
    }
}

extern "C" void kernel_launch(void* const* d_in, const int* in_sizes, int n_in,
                              void* d_out, int out_size, void* d_ws, size_t ws_size,
                              hipStream_t stream) {
    const float* x  = (const float*)d_in[0];
    const float* Wq = (const float*)d_in[1];
    const float* bq = (const float*)d_in[2];
    const float* Wk = (const float*)d_in[3];
    const float* bk = (const float*)d_in[4];
    const float* pm = (const float*)d_in[5];
    const float* ls = (const float*)d_in[6];
    float* out = (float*)d_out;

    char* w = (char*)d_ws;
    __hip_bfloat16* wbuf = (__hip_bfloat16*)w;  w += (size_t)64 * 4096 * 2;             // 0.5 MB
    __hip_bfloat16* prtF = (__hip_bfloat16*)w;  w += (size_t)24 * 64 * 64 * 8 * 2;      // 1.6 MB
    __hip_bfloat16* qf   = (__hip_bfloat16*)w;  w += (size_t)BH * LB * 64 * 2;          // 8.4 MB
    __hip_bfloat16* kT   = (__hip_bfloat16*)w;  w += (size_t)BH * 4 * 64 * 64 * 8 * 2;  // 8.4 MB
    float*          gpart = (float*)w;          w += (size_t)BH * NCK * NROW * 64 * 4;  // 6.3 MB
    float*          gw    = (float*)w;                                                  // 0.4 MB

    prep_misc<<<dim3(160), dim3(256), 0, stream>>>(Wq, Wk, pm, ls, wbuf, prtF);
    proj_fused<<<dim3(128, 8), dim3(256), 0, stream>>>(x, wbuf, bq, bk, qf, kT);
    conv_mfma<<<dim3(32, 4), dim3(256), 0, stream>>>(prtF, kT, gpart);
    conv_combine<<<dim3(384), dim3(256), 0, stream>>>(gpart, gw);
    final_kernel<<<dim3(4096), dim3(256), 0, stream>>>(qf, gw, out);
}

// Round 17
// 39.933 us; speedup vs baseline: 1.8150x; 1.0914x over previous
//
#include <hip/hip_runtime.h>
#include <hip/hip_bf16.h>

#define LB 2048
#define DB 256
#define HB 8
#define BH 32     // B*H
#define NG 19     // prior nodes: node g at i = 128*(g-1)
#define NROW 48   // A rows: 0-18 P, 19-37 P*d, 38-47 zero
#define NCK 16    // conv K-chunks (128 m each)

typedef __attribute__((ext_vector_type(8))) short short8;
typedef __attribute__((ext_vector_type(4))) short short4v;
typedef __attribute__((ext_vector_type(4))) float floatx4;

static __device__ __forceinline__ short bfbits(float f) {
    __hip_bfloat16 h = __float2bfloat16(f);
    return *reinterpret_cast<short*>(&h);
}

// ---------------- prep_all: x fragments (0-511) + W fragments (512-575) + prior A (576-671)
__global__ __launch_bounds__(256) void prep_all(
    const float* __restrict__ x, const float* __restrict__ Wq,
    const float* __restrict__ Wk, const float* __restrict__ pm,
    const float* __restrict__ ls,
    __hip_bfloat16* __restrict__ xb, __hip_bfloat16* __restrict__ wb,
    __hip_bfloat16* __restrict__ prtF)
{
    if (blockIdx.x < 512) {
        // x fp32 [8192][256] -> bf16 fragment tiles [512][4096] (coalesced)
        const int t   = blockIdx.x;
        const int ksg = threadIdx.x & 31;
#pragma unroll
        for (int p = 0; p < 2; ++p) {
            const int l = (threadIdx.x >> 5) + 8 * p;
            const float* src = x + (size_t)(t * 16 + l) * DB + ksg * 8;
            const float4 v0 = *reinterpret_cast<const float4*>(src);
            const float4 v1 = *reinterpret_cast<const float4*>(src + 4);
            short8 o;
            o[0] = bfbits(v0.x); o[1] = bfbits(v0.y); o[2] = bfbits(v0.z); o[3] = bfbits(v0.w);
            o[4] = bfbits(v1.x); o[5] = bfbits(v1.y); o[6] = bfbits(v1.z); o[7] = bfbits(v1.w);
            *(reinterpret_cast<short8*>(xb + (size_t)t * 4096) + (ksg * 16 + l)) = o;
        }
        return;
    }
    if (blockIdx.x < 576) {
        // W [256][512] -> transposed bf16 fragment tiles
        const int blk = blockIdx.x - 512;         // 0..63
        const float* W = (blk & 32) ? Wk : Wq;
        const int nbase = (blk & 31) * 16;
#pragma unroll
        for (int cc = 0; cc < 2; ++cc) {
            const int c  = threadIdx.x + cc * 256;
            const int n  = nbase + (c & 15);
            const int k0 = (c >> 4) * 8;
            short8 o;
#pragma unroll
            for (int e = 0; e < 8; ++e) o[e] = bfbits(W[(size_t)(k0 + e) * 512 + n]);
            *(reinterpret_cast<short8*>(wb + (size_t)blk * 4096) + c) = o;
        }
        return;
    }
    // prior A-fragments: blk2 = (h, gt, ms-quarter)
    const int blk2 = blockIdx.x - 576;            // 0..95
    const int h    = blk2 / 12;
    const int rem  = blk2 - h * 12;
    const int gt   = rem >> 2;
    const int msq  = rem & 3;
    const int wv   = threadIdx.x >> 6;
    const int l    = threadIdx.x & 63;

    const float mu        = pm[h];
    const float inv_sigma = __expf(-ls[h]);
    const float coef = 0.125f * inv_sigma * (1.0f / 2.5066282f);

    const int row = gt * 16 + (l & 15);           // A row 0..47
#pragma unroll
    for (int it = 0; it < 4; ++it) {
        const int ms = msq * 16 + wv * 4 + it;    // 0..63
        const int m0 = ms * 32 + (l >> 4) * 8;
        short8 o;
#pragma unroll
        for (int e = 0; e < 8; ++e) {
            float val = 0.f;
            if (row < 38) {
                const int g = (row < 19) ? row : row - 19;
                const float d = (float)(m0 + e - 128 * g + 128);
                const float t = (d - mu) * inv_sigma;
                const float P = coef * __expf(-0.5f * t * t);
                val = (row < 19) ? P : P * d;
            }
            o[e] = bfbits(val);
        }
        reinterpret_cast<short8*>(prtF)[(size_t)((h * 3 + gt) * 64 + ms) * 64 + l] = o;
    }
}

// ---------------- proj: A-fragments from global xb (coalesced); q -> row-major, k -> kT
__global__ __launch_bounds__(256) void proj_mfma(
    const __hip_bfloat16* __restrict__ xb, const __hip_bfloat16* __restrict__ wb,
    const float* __restrict__ bq, const float* __restrict__ bk,
    __hip_bfloat16* __restrict__ qf, __hip_bfloat16* __restrict__ kT)
{
    __shared__ __align__(16) __hip_bfloat16 ot[64][136];   // 17.4 KB transpose buffer

    const int rt   = blockIdx.x;              // 64-row block
    const int cg   = blockIdx.y;              // 0-3: q, 4-7: k
    const int wave = threadIdx.x >> 6;
    const int lane = threadIdx.x & 63;
    const int kg   = lane >> 4;
    const int l15  = lane & 15;

    // x fragments straight from global (16B/lane, layout proven R4-R13)
    const short8* xp = reinterpret_cast<const short8*>(xb)
                     + (size_t)(rt * 4 + wave) * 512 + lane;
    short8 a[8];
#pragma unroll
    for (int kb = 0; kb < 8; ++kb) a[kb] = xp[kb * 64];

    const int b_   = rt >> 5;
    const int gct0 = cg * 8;
    const short8* wp = reinterpret_cast<const short8*>(wb) + lane;

    short8 wA[8], wB[8];
#pragma unroll
    for (int kb = 0; kb < 8; ++kb) wA[kb] = wp[(size_t)(gct0 * 8 + kb) * 64];

#define PROJ_STEP(CURW, NXTW, CT)                                                     \
    {                                                                                 \
        if ((CT) < 7) {                                                               \
            _Pragma("unroll")                                                         \
            for (int kb = 0; kb < 8; ++kb)                                            \
                NXTW[kb] = wp[(size_t)((gct0 + (CT) + 1) * 8 + kb) * 64];             \
        }                                                                             \
        floatx4 acc = {0.f, 0.f, 0.f, 0.f};                                           \
        _Pragma("unroll")                                                             \
        for (int kb = 0; kb < 8; ++kb)                                                \
            acc = __builtin_amdgcn_mfma_f32_16x16x32_bf16(CURW[kb], a[kb], acc, 0, 0, 0); \
        const int h   = ((gct0 + (CT)) & 31) >> 2;                                    \
        const float bias = (cg < 4 ? bq : bk)[h];                                     \
        short4v o;                                                                    \
        _Pragma("unroll")                                                             \
        for (int r = 0; r < 4; ++r) o[r] = bfbits(acc[r] + bias);                     \
        *reinterpret_cast<short4v*>(&ot[wave * 16 + l15][(CT) * 16 + 4 * kg]) = o;    \
    }

    PROJ_STEP(wA, wB, 0)
    PROJ_STEP(wB, wA, 1)
    PROJ_STEP(wA, wB, 2)
    PROJ_STEP(wB, wA, 3)
    PROJ_STEP(wA, wB, 4)
    PROJ_STEP(wB, wA, 5)
    PROJ_STEP(wA, wB, 6)
    PROJ_STEP(wB, wA, 7)
#undef PROJ_STEP

    __syncthreads();

    if (cg < 4) {
        // q: coalesced row-major copy-out (verified R15/R16)
        const int h0 = (cg & 3) * 2;
        const int rbase = (rt & 31) * 64;
#pragma unroll
        for (int it = 0; it < 8; ++it) {
            const int cidx = threadIdx.x + it * 256;
            const int row  = cidx >> 5;
            const int sub  = cidx & 31;
            const int hoff = sub >> 4;
            const int ch64 = (sub & 15) * 4;
            const short4v v = *reinterpret_cast<const short4v*>(&ot[row][sub * 4]);
            const size_t dst = (((size_t)(b_ * HB + h0 + hoff) << 11) + rbase + row) * 64 + ch64;
            *reinterpret_cast<short4v*>(qf + dst) = v;
        }
    } else {
        // k: emit kT B-fragments (verified R16)
        const int hoff = wave >> 1;
        const int msb  = wave & 1;
        const int h0   = (cg & 3) * 2;
        const int bh   = b_ * HB + h0 + hoff;
        const int msG  = (rt & 31) * 2 + msb;
        const int rowb = msb * 32 + (lane >> 4) * 8;
        const int colb = hoff * 64 + l15;
#pragma unroll
        for (int ct = 0; ct < 4; ++ct) {
            short8 o;
#pragma unroll
            for (int e = 0; e < 8; ++e)
                o[e] = *reinterpret_cast<const short*>(&ot[rowb + e][colb + ct * 16]);
            reinterpret_cast<short8*>(kT)[(size_t)((bh * 4 + ct) * 64 + msG) * 64 + lane] = o;
        }
    }
}

// ---------------- conv via MFMA: G[48 x 64] = prior[48 x 2048] . kT (unchanged R16)
__global__ __launch_bounds__(256, 2) void conv_mfma(
    const __hip_bfloat16* __restrict__ prtF, const __hip_bfloat16* __restrict__ kT,
    float* __restrict__ gpart)
{
    const int bh   = blockIdx.x;
    const int wv   = threadIdx.x >> 6;
    const int lane = threadIdx.x & 63;
    const int ck   = blockIdx.y * 4 + wv;     // 0..15
    const int h    = bh & 7;

    const short8* A = reinterpret_cast<const short8*>(prtF);
    const short8* B = reinterpret_cast<const short8*>(kT);

    floatx4 acc[3][4];
#pragma unroll
    for (int gt = 0; gt < 3; ++gt)
#pragma unroll
        for (int ct = 0; ct < 4; ++ct) acc[gt][ct] = (floatx4){0.f, 0.f, 0.f, 0.f};

#pragma unroll
    for (int s = 0; s < 4; ++s) {
        const int ms = ck * 4 + s;
        short8 af[3], bf[4];
#pragma unroll
        for (int gt = 0; gt < 3; ++gt)
            af[gt] = A[(size_t)((h * 3 + gt) * 64 + ms) * 64 + lane];
#pragma unroll
        for (int ct = 0; ct < 4; ++ct)
            bf[ct] = B[(size_t)((bh * 4 + ct) * 64 + ms) * 64 + lane];
#pragma unroll
        for (int gt = 0; gt < 3; ++gt)
#pragma unroll
            for (int ct = 0; ct < 4; ++ct)
                acc[gt][ct] = __builtin_amdgcn_mfma_f32_16x16x32_bf16(af[gt], bf[ct], acc[gt][ct], 0, 0, 0);
    }

    const int kg = lane >> 4, l15 = lane & 15;
    float* gp = gpart + (size_t)(bh * NCK + ck) * (NROW * 64);
#pragma unroll
    for (int gt = 0; gt < 3; ++gt)
#pragma unroll
        for (int ct = 0; ct < 4; ++ct)
#pragma unroll
            for (int r = 0; r < 4; ++r)
                gp[(gt * 16 + 4 * kg + r) * 64 + ct * 16 + l15] = acc[gt][ct][r];
}

// ---------------- combine 16 K-chunks: gw[bh][48][64] (unchanged R16)
__global__ __launch_bounds__(256) void conv_combine(const float* __restrict__ gpart,
                                                    float* __restrict__ gw)
{
    const int j   = blockIdx.x * 256 + threadIdx.x;   // 0..98303 (grid exact)
    const int bh  = j / 3072;
    const int idx = j - bh * 3072;
    const float* gp = gpart + (size_t)bh * NCK * 3072 + idx;
    float s = 0.f;
#pragma unroll
    for (int c = 0; c < NCK; ++c) s += gp[(size_t)c * 3072];
    gw[j] = s;
}

// ---------------- final: Catmull-Rom interp + q-dot (unchanged R16)
__global__ __launch_bounds__(256) void final_kernel(
    const __hip_bfloat16* __restrict__ qf, const float* __restrict__ gw,
    float* __restrict__ out)
{
    const int row = blockIdx.x * 16 + (threadIdx.x >> 4);  // bh*2048 + i
    const int l15 = threadIdx.x & 15;
    const int bh  = row >> 11;
    const int i   = row & (LB - 1);
    const int b   = bh >> 3;
    const int h   = bh & 7;

    const short4v q4 = reinterpret_cast<const short4v*>(qf)[(size_t)row * 16 + l15];
    float q[4];
#pragma unroll
    for (int e = 0; e < 4; ++e) {
        const unsigned short u16 = (unsigned short)q4[e];
        const unsigned int bits = ((unsigned int)u16) << 16;
        q[e] = __builtin_bit_cast(float, bits);
    }

    const int   cell = i >> 7;
    const float u  = (float)(i & 127) * (1.0f / 128.0f);
    const float u2 = u * u, u3 = u2 * u;
    const float c0 = -0.5f * u + u2 - 0.5f * u3;
    const float c1 = 1.0f - 2.5f * u2 + 1.5f * u3;
    const float c2 = 0.5f * u + 2.0f * u2 - 1.5f * u3;
    const float c3 = -0.5f * u2 + 0.5f * u3;

    const float4* g4 = reinterpret_cast<const float4*>(gw + (size_t)bh * 3072) + l15;
    const float4 n0 = g4[(cell + 0) * 16], n1 = g4[(cell + 1) * 16];
    const float4 n2 = g4[(cell + 2) * 16], n3 = g4[(cell + 3) * 16];
    const float4 w0 = g4[(19 + cell + 0) * 16], w1 = g4[(19 + cell + 1) * 16];
    const float4 w2 = g4[(19 + cell + 2) * 16], w3 = g4[(19 + cell + 3) * 16];

    float D = q[0] * (c0 * n0.x + c1 * n1.x + c2 * n2.x + c3 * n3.x)
            + q[1] * (c0 * n0.y + c1 * n1.y + c2 * n2.y + c3 * n3.y)
            + q[2] * (c0 * n0.z + c1 * n1.z + c2 * n2.z + c3 * n3.z)
            + q[3] * (c0 * n0.w + c1 * n1.w + c2 * n2.w + c3 * n3.w);
    float N = q[0] * (c0 * w0.x + c1 * w1.x + c2 * w2.x + c3 * w3.x)
            + q[1] * (c0 * w0.y + c1 * w1.y + c2 * w2.y + c3 * w3.y)
            + q[2] * (c0 * w0.z + c1 * w1.z + c2 * w2.z + c3 * w3.z)
            + q[3] * (c0 * w0.w + c1 * w1.w + c2 * w2.w + c3 * w3.w);

#pragma unroll
    for (int off = 8; off >= 1; off >>= 1) {
        D += __shfl_xor(D, off, 64);
        N += __shfl_xor(N, off, 64);
    }
    if (l15 == 0) {
        const float C = (float)(2096128 - 2048 * i);   // sum_m (m - i), exact
        out[((size_t)(b * LB + i)) * HB + h] = (C + N) / (2048.0f + D);
    }
}

extern "C" void kernel_launch(void* const* d_in, const int* in_sizes, int n_in,
                              void* d_out, int out_size, void* d_ws, size_t ws_size,
                              hipStream_t stream) {
    const float* x  = (const float*)d_in[0];
    const float* Wq = (const float*)d_in[1];
    const float* bq = (const float*)d_in[2];
    const float* Wk = (const float*)d_in[3];
    const float* bk = (const float*)d_in[4];
    const float* pm = (const float*)d_in[5];
    const float* ls = (const float*)d_in[6];
    float* out = (float*)d_out;

    char* w = (char*)d_ws;
    __hip_bfloat16* xb   = (__hip_bfloat16*)w;  w += (size_t)512 * 4096 * 2;            // 4.2 MB
    __hip_bfloat16* wbuf = (__hip_bfloat16*)w;  w += (size_t)64 * 4096 * 2;             // 0.5 MB
    __hip_bfloat16* prtF = (__hip_bfloat16*)w;  w += (size_t)24 * 64 * 64 * 8 * 2;      // 1.6 MB
    __hip_bfloat16* qf   = (__hip_bfloat16*)w;  w += (size_t)BH * LB * 64 * 2;          // 8.4 MB
    __hip_bfloat16* kT   = (__hip_bfloat16*)w;  w += (size_t)BH * 4 * 64 * 64 * 8 * 2;  // 8.4 MB
    float*          gpart = (float*)w;          w += (size_t)BH * NCK * NROW * 64 * 4;  // 6.3 MB
    float*          gw    = (float*)w;                                                  // 0.4 MB

    prep_all<<<dim3(672), dim3(256), 0, stream>>>(x, Wq, Wk, pm, ls, xb, wbuf, prtF);
    proj_mfma<<<dim3(128, 8), dim3(256), 0, stream>>>(xb, wbuf, bq, bk, qf, kT);
    conv_mfma<<<dim3(32, 4), dim3(256), 0, stream>>>(prtF, kT, gpart);
    conv_combine<<<dim3(384), dim3(256), 0, stream>>>(gpart, gw);
    final_kernel<<<dim3(4096), dim3(256), 0, stream>>>(qf, gw, out);
}